// Round 1
// baseline (2044.402 us; speedup 1.0000x reference)
//
#include <hip/hip_runtime.h>
#include <math.h>

#define B_TOTAL 262144
#define D 16
#define CTX 128
#define H 192
#define IN_DIM 145   // D + CTX + 1
#define R 16         // rows per block
#define BLOCK 256

// LDS budget: inp 145*16*4=9280 + eps 1024 + 4*(192*16*4)=49152  -> 59456 B (<64KB)

__global__ __launch_bounds__(BLOCK) void odefunc_kernel(
    const float* __restrict__ t_ptr,
    const float* __restrict__ y,
    const float* __restrict__ h,
    const float* __restrict__ eps,
    const float* __restrict__ W1, const float* __restrict__ b1,
    const float* __restrict__ W2, const float* __restrict__ b2,
    const float* __restrict__ W3, const float* __restrict__ b3,
    float* __restrict__ out_f,      // B*D
    float* __restrict__ out_dlogp)  // B
{
    __shared__ float inp[IN_DIM][R];
    __shared__ float eps_l[D][R];
    __shared__ float a1[H][R];
    __shared__ float du1[H][R];
    __shared__ float a2[H][R];
    __shared__ float du2[H][R];

    const int tid = threadIdx.x;
    const int r0  = blockIdx.x * R;

    // ---------------- load phase ----------------
    {
        int r = tid >> 4, k = tid & 15;           // 256 threads = 16 rows x 16 cols
        inp[k][r]   = y[(size_t)(r0 + r) * D + k];
        eps_l[k][r] = eps[(size_t)(r0 + r) * D + k];
    }
    #pragma unroll
    for (int i = 0; i < (R * CTX) / BLOCK; ++i) { // 8 iters
        int idx = tid + i * BLOCK;
        int r = idx >> 7, c = idx & 127;
        inp[D + c][r] = h[(size_t)(r0 + r) * CTX + c];
    }
    if (tid < R) inp[IN_DIM - 1][tid] = t_ptr[0];
    __syncthreads();

    // ---------------- layer 1 ----------------
    if (tid < H) {
        const int j = tid;
        float z[R], u[R];
        float bb = b1[j];
        #pragma unroll
        for (int r = 0; r < R; ++r) { z[r] = bb; u[r] = 0.f; }

        for (int k = 0; k < IN_DIM; ++k) {
            float w = W1[k * H + j];
            const float4* ip = (const float4*)&inp[k][0];
            #pragma unroll
            for (int q = 0; q < R / 4; ++q) {
                float4 v = ip[q];
                z[q*4+0] += v.x * w; z[q*4+1] += v.y * w;
                z[q*4+2] += v.z * w; z[q*4+3] += v.w * w;
            }
        }
        // tangent: only first D rows of W1 (d(inp) = [eps, 0, 0])
        for (int k = 0; k < D; ++k) {
            float w = W1[k * H + j];
            const float4* ep = (const float4*)&eps_l[k][0];
            #pragma unroll
            for (int q = 0; q < R / 4; ++q) {
                float4 v = ep[q];
                u[q*4+0] += v.x * w; u[q*4+1] += v.y * w;
                u[q*4+2] += v.z * w; u[q*4+3] += v.w * w;
            }
        }
        #pragma unroll
        for (int r = 0; r < R; ++r) {
            float x   = z[r];
            float phi = 0.5f * (1.0f + erff(x * 0.70710678118654752f)); // CDF
            float pdf = 0.39894228040143268f * __expf(-0.5f * x * x);
            a1[j][r]  = x * phi;                 // gelu(x)
            du1[j][r] = u[r] * (phi + x * pdf);  // gelu'(x) * tangent
        }
    }
    __syncthreads();

    // ---------------- layer 2 ----------------
    if (tid < H) {
        const int j = tid;
        float z[R], u[R];
        float bb = b2[j];
        #pragma unroll
        for (int r = 0; r < R; ++r) { z[r] = bb; u[r] = 0.f; }

        for (int k = 0; k < H; ++k) {
            float w = W2[k * H + j];
            const float4* ap = (const float4*)&a1[k][0];
            const float4* dp = (const float4*)&du1[k][0];
            #pragma unroll
            for (int q = 0; q < R / 4; ++q) {
                float4 av = ap[q];
                float4 dv = dp[q];
                z[q*4+0] += av.x * w; z[q*4+1] += av.y * w;
                z[q*4+2] += av.z * w; z[q*4+3] += av.w * w;
                u[q*4+0] += dv.x * w; u[q*4+1] += dv.y * w;
                u[q*4+2] += dv.z * w; u[q*4+3] += dv.w * w;
            }
        }
        #pragma unroll
        for (int r = 0; r < R; ++r) {
            float x   = z[r];
            float phi = 0.5f * (1.0f + erff(x * 0.70710678118654752f));
            float pdf = 0.39894228040143268f * __expf(-0.5f * x * x);
            a2[j][r]  = x * phi;
            du2[j][r] = u[r] * (phi + x * pdf);
        }
    }
    __syncthreads();

    // ---------------- layer 3 + trace ----------------
    {
        const int r = tid >> 4, d = tid & 15;     // 16 rows x 16 outputs
        float facc = b3[d];
        float jacc = 0.f;
        for (int k = 0; k < H; ++k) {
            float w = W3[k * D + d];
            facc += a2[k][r] * w;
            jacc += du2[k][r] * w;
        }
        out_f[(size_t)(r0 + r) * D + d] = facc;

        float p = jacc * eps_l[d][r];
        #pragma unroll
        for (int m = 1; m < 16; m <<= 1) p += __shfl_xor(p, m, 16);
        if (d == 0) out_dlogp[r0 + r] = -p;
    }
}

extern "C" void kernel_launch(void* const* d_in, const int* in_sizes, int n_in,
                              void* d_out, int out_size, void* d_ws, size_t ws_size,
                              hipStream_t stream)
{
    const float* t   = (const float*)d_in[0];
    const float* y   = (const float*)d_in[1];
    // d_in[2] = logp (unused by the ODE function)
    const float* h   = (const float*)d_in[3];
    const float* eps = (const float*)d_in[4];
    const float* W1  = (const float*)d_in[5];
    const float* b1  = (const float*)d_in[6];
    const float* W2  = (const float*)d_in[7];
    const float* b2  = (const float*)d_in[8];
    const float* W3  = (const float*)d_in[9];
    const float* b3  = (const float*)d_in[10];

    float* out       = (float*)d_out;
    float* out_f     = out;                                   // B*D
    float* out_dlogp = out + (size_t)B_TOTAL * D;             // B
    float* out_dh    = out + (size_t)B_TOTAL * (D + 1);       // B*CTX, all zeros

    hipMemsetAsync(out_dh, 0, (size_t)B_TOTAL * CTX * sizeof(float), stream);

    odefunc_kernel<<<B_TOTAL / R, BLOCK, 0, stream>>>(
        t, y, h, eps, W1, b1, W2, b2, W3, b3, out_f, out_dlogp);
}

// Round 2
// 549.781 us; speedup vs baseline: 3.7186x; 3.7186x over previous
//
#include <hip/hip_runtime.h>
#include <hip/hip_bf16.h>
#include <math.h>

#define B_TOTAL 262144
#define D 16
#define CTX 128
#define H 192
#define IN_DIM 145
#define KP1 160      // layer-1 K padded to 5 chunks of 32
#define M 32         // rows per block
#define BLOCK 256

typedef __attribute__((ext_vector_type(8))) short bf16x8;
typedef __attribute__((ext_vector_type(4))) float f32x4;

#define MFMA(a, b, c) __builtin_amdgcn_mfma_f32_16x16x32_bf16((a), (b), (c), 0, 0, 0)

__device__ __forceinline__ unsigned short f2bf(float f) {
    __hip_bfloat16 h = __float2bfloat16(f);
    return *reinterpret_cast<unsigned short*>(&h);
}
__device__ __forceinline__ float bf2f(unsigned short u) {
    __hip_bfloat16 h;
    *reinterpret_cast<unsigned short*>(&h) = u;
    return __bfloat162float(h);
}

// ---------- pre-kernel: transpose weights to [N][K] bf16 in d_ws ----------
// Wt1: [192][160] at elem 0      (k>=145 zero-padded)
// Wt2: [192][192] at elem 30720
// Wt3: [16][192]  at elem 67584
__global__ void prep_weights(const float* __restrict__ W1,
                             const float* __restrict__ W2,
                             const float* __restrict__ W3,
                             unsigned short* __restrict__ wt)
{
    int i = blockIdx.x * 256 + threadIdx.x;
    if (i < H * KP1) {
        int n = i / KP1, k = i % KP1;
        wt[i] = (k < IN_DIM) ? f2bf(W1[k * H + n]) : (unsigned short)0;
        return;
    }
    i -= H * KP1;
    if (i < H * H) {
        int n = i / H, k = i % H;
        wt[30720 + i] = f2bf(W2[k * H + n]);
        return;
    }
    i -= H * H;
    if (i < D * H) {
        int n = i / H, k = i % H;
        wt[67584 + i] = f2bf(W3[k * D + n]);
    }
}

// ---------- main kernel ----------
__global__ __launch_bounds__(BLOCK, 2) void odefunc_mfma(
    const float* __restrict__ t_ptr,
    const float* __restrict__ y,
    const float* __restrict__ h,
    const float* __restrict__ eps,
    const float* __restrict__ b1,
    const float* __restrict__ b2,
    const float* __restrict__ b3,
    const unsigned short* __restrict__ wt,
    float* __restrict__ out_f,
    float* __restrict__ out_dlogp)
{
    // LDS: 21504 + 5120 + 51200 = 77824 B -> 2 blocks/CU
    __shared__ __align__(16) unsigned short Xh[M][168], Xl[M][168];
    __shared__ __align__(16) unsigned short Th[M][40],  Tl[M][40];
    __shared__ __align__(16) unsigned short Ah[M][200], Al[M][200];
    __shared__ __align__(16) unsigned short Uh[M][200], Ul[M][200];

    const int tid  = threadIdx.x;
    const int lane = tid & 63;
    const int wv   = tid >> 6;
    const int quad = lane >> 4;
    const int l16  = lane & 15;
    const size_t r0 = (size_t)blockIdx.x * M;

    const unsigned short* Wt1 = wt;
    const unsigned short* Wt2 = wt + 30720;
    const unsigned short* Wt3 = wt + 67584;

    // ------------- stage inputs (hi/lo split) -------------
    for (int idx = tid; idx < M * D; idx += BLOCK) {      // y, eps
        int r = idx >> 4, d = idx & 15;
        float v = y[(r0 + r) * D + d];
        unsigned short hv = f2bf(v);
        Xh[r][d] = hv; Xl[r][d] = f2bf(v - bf2f(hv));
        float e = eps[(r0 + r) * D + d];
        unsigned short he = f2bf(e);
        Th[r][d] = he; Tl[r][d] = f2bf(e - bf2f(he));
    }
    for (int idx = tid; idx < M * CTX; idx += BLOCK) {    // h
        int r = idx >> 7, c = idx & 127;
        float v = h[(r0 + r) * CTX + c];
        unsigned short hv = f2bf(v);
        Xh[r][D + c] = hv; Xl[r][D + c] = f2bf(v - bf2f(hv));
    }
    {
        float tv = t_ptr[0];
        unsigned short thi = f2bf(tv), tlo = f2bf(tv - bf2f(thi));
        for (int idx = tid; idx < M * 16; idx += BLOCK) { // t col + zero pad
            int r = idx >> 4, k = idx & 15;
            if (k == 0) { Xh[r][144] = thi; Xl[r][144] = tlo; }
            if (k < 15) { Xh[r][145 + k] = 0; Xl[r][145 + k] = 0; }
            Th[r][D + k] = 0; Tl[r][D + k] = 0;
        }
    }
    __syncthreads();

    const f32x4 zf = {0.f, 0.f, 0.f, 0.f};

    // ------------- layer 1 -------------
    f32x4 z[2][3], u[2][3];
    #pragma unroll
    for (int rt = 0; rt < 2; ++rt)
        #pragma unroll
        for (int j = 0; j < 3; ++j) { z[rt][j] = zf; u[rt][j] = zf; }

    bf16x8 w1f[3][5];
    #pragma unroll
    for (int j = 0; j < 3; ++j) {
        int n = (wv * 3 + j) * 16 + l16;
        #pragma unroll
        for (int kc = 0; kc < 5; ++kc)
            w1f[j][kc] = *(const bf16x8*)(Wt1 + n * KP1 + kc * 32 + quad * 8);
    }
    #pragma unroll
    for (int kc = 0; kc < 5; ++kc) {
        #pragma unroll
        for (int rt = 0; rt < 2; ++rt) {
            int m = rt * 16 + l16, o = kc * 32 + quad * 8;
            bf16x8 ah = *(const bf16x8*)&Xh[m][o];
            bf16x8 al = *(const bf16x8*)&Xl[m][o];
            #pragma unroll
            for (int j = 0; j < 3; ++j) {
                z[rt][j] = MFMA(ah, w1f[j][kc], z[rt][j]);
                z[rt][j] = MFMA(al, w1f[j][kc], z[rt][j]);
            }
        }
    }
    #pragma unroll
    for (int rt = 0; rt < 2; ++rt) {                      // tangent: K=16 (chunk 0)
        int m = rt * 16 + l16, o = quad * 8;
        bf16x8 th = *(const bf16x8*)&Th[m][o];
        bf16x8 tl = *(const bf16x8*)&Tl[m][o];
        #pragma unroll
        for (int j = 0; j < 3; ++j) {
            u[rt][j] = MFMA(th, w1f[j][0], u[rt][j]);
            u[rt][j] = MFMA(tl, w1f[j][0], u[rt][j]);
        }
    }
    // epilogue 1: bias + gelu -> A/U planes (no barrier needed: disjoint LDS)
    #pragma unroll
    for (int j = 0; j < 3; ++j) {
        int n = (wv * 3 + j) * 16 + l16;
        float bb = b1[n];
        #pragma unroll
        for (int rt = 0; rt < 2; ++rt)
            #pragma unroll
            for (int rg = 0; rg < 4; ++rg) {
                int m = rt * 16 + quad * 4 + rg;
                float x   = z[rt][j][rg] + bb;
                float phi = 0.5f * (1.0f + erff(x * 0.70710678118654752f));
                float pdf = 0.39894228040143268f * __expf(-0.5f * x * x);
                float a   = x * phi;
                float du  = u[rt][j][rg] * (phi + x * pdf);
                unsigned short ha = f2bf(a);
                Ah[m][n] = ha; Al[m][n] = f2bf(a - bf2f(ha));
                unsigned short hu = f2bf(du);
                Uh[m][n] = hu; Ul[m][n] = f2bf(du - bf2f(hu));
            }
    }
    __syncthreads();

    // ------------- layer 2 -------------
    f32x4 z2[2][3], u2[2][3];
    #pragma unroll
    for (int rt = 0; rt < 2; ++rt)
        #pragma unroll
        for (int j = 0; j < 3; ++j) { z2[rt][j] = zf; u2[rt][j] = zf; }

    bf16x8 w2f[3][6];
    #pragma unroll
    for (int j = 0; j < 3; ++j) {
        int n = (wv * 3 + j) * 16 + l16;
        #pragma unroll
        for (int kc = 0; kc < 6; ++kc)
            w2f[j][kc] = *(const bf16x8*)(Wt2 + n * H + kc * 32 + quad * 8);
    }
    #pragma unroll
    for (int kc = 0; kc < 6; ++kc) {
        #pragma unroll
        for (int rt = 0; rt < 2; ++rt) {
            int m = rt * 16 + l16, o = kc * 32 + quad * 8;
            bf16x8 ah = *(const bf16x8*)&Ah[m][o];
            bf16x8 al = *(const bf16x8*)&Al[m][o];
            bf16x8 uh = *(const bf16x8*)&Uh[m][o];
            bf16x8 ul = *(const bf16x8*)&Ul[m][o];
            #pragma unroll
            for (int j = 0; j < 3; ++j) {
                z2[rt][j] = MFMA(ah, w2f[j][kc], z2[rt][j]);
                z2[rt][j] = MFMA(al, w2f[j][kc], z2[rt][j]);
                u2[rt][j] = MFMA(uh, w2f[j][kc], u2[rt][j]);
                u2[rt][j] = MFMA(ul, w2f[j][kc], u2[rt][j]);
            }
        }
    }
    __syncthreads();   // all reads of a1/du1 done before overwrite
    #pragma unroll
    for (int j = 0; j < 3; ++j) {
        int n = (wv * 3 + j) * 16 + l16;
        float bb = b2[n];
        #pragma unroll
        for (int rt = 0; rt < 2; ++rt)
            #pragma unroll
            for (int rg = 0; rg < 4; ++rg) {
                int m = rt * 16 + quad * 4 + rg;
                float x   = z2[rt][j][rg] + bb;
                float phi = 0.5f * (1.0f + erff(x * 0.70710678118654752f));
                float pdf = 0.39894228040143268f * __expf(-0.5f * x * x);
                float a   = x * phi;
                float du  = u2[rt][j][rg] * (phi + x * pdf);
                unsigned short ha = f2bf(a);
                Ah[m][n] = ha; Al[m][n] = f2bf(a - bf2f(ha));
                unsigned short hu = f2bf(du);
                Uh[m][n] = hu; Ul[m][n] = f2bf(du - bf2f(hu));
            }
    }
    __syncthreads();

    // ------------- layer 3 + outputs -------------
    // wave 0: rows 0-15 value | wave 1: rows 0-15 tangent | wave 2/3: rows 16-31
    {
        const int stream = wv & 1, rt = wv >> 1;
        const unsigned short (*Ph)[200] = stream ? Uh : Ah;
        const unsigned short (*Pl)[200] = stream ? Ul : Al;

        bf16x8 w3f[6];
        #pragma unroll
        for (int kc = 0; kc < 6; ++kc)
            w3f[kc] = *(const bf16x8*)(Wt3 + l16 * H + kc * 32 + quad * 8);

        f32x4 acc = zf;
        #pragma unroll
        for (int kc = 0; kc < 6; ++kc) {
            int m = rt * 16 + l16, o = kc * 32 + quad * 8;
            bf16x8 xh = *(const bf16x8*)&Ph[m][o];
            bf16x8 xl = *(const bf16x8*)&Pl[m][o];
            acc = MFMA(xh, w3f[kc], acc);
            acc = MFMA(xl, w3f[kc], acc);
        }

        if (stream == 0) {
            float bb = b3[l16];
            #pragma unroll
            for (int rg = 0; rg < 4; ++rg) {
                int m = rt * 16 + quad * 4 + rg;
                out_f[(r0 + m) * D + l16] = acc[rg] + bb;
            }
        } else {
            float pr[4];
            #pragma unroll
            for (int rg = 0; rg < 4; ++rg) {
                int m = rt * 16 + quad * 4 + rg;
                pr[rg] = acc[rg] * eps[(r0 + m) * D + l16];
            }
            #pragma unroll
            for (int sh = 1; sh < 16; sh <<= 1)
                #pragma unroll
                for (int rg = 0; rg < 4; ++rg)
                    pr[rg] += __shfl_xor(pr[rg], sh, 64);
            if (l16 == 0)
                #pragma unroll
                for (int rg = 0; rg < 4; ++rg)
                    out_dlogp[r0 + rt * 16 + quad * 4 + rg] = -pr[rg];
        }
    }
}

extern "C" void kernel_launch(void* const* d_in, const int* in_sizes, int n_in,
                              void* d_out, int out_size, void* d_ws, size_t ws_size,
                              hipStream_t stream)
{
    const float* t   = (const float*)d_in[0];
    const float* y   = (const float*)d_in[1];
    const float* h   = (const float*)d_in[3];
    const float* eps = (const float*)d_in[4];
    const float* W1  = (const float*)d_in[5];
    const float* b1  = (const float*)d_in[6];
    const float* W2  = (const float*)d_in[7];
    const float* b2  = (const float*)d_in[8];
    const float* W3  = (const float*)d_in[9];
    const float* b3  = (const float*)d_in[10];

    float* out       = (float*)d_out;
    float* out_f     = out;
    float* out_dlogp = out + (size_t)B_TOTAL * D;
    float* out_dh    = out + (size_t)B_TOTAL * (D + 1);

    unsigned short* wt = (unsigned short*)d_ws;

    hipMemsetAsync(out_dh, 0, (size_t)B_TOTAL * CTX * sizeof(float), stream);

    int prep_elems = H * KP1 + H * H + D * H;   // 70656
    prep_weights<<<(prep_elems + 255) / 256, 256, 0, stream>>>(W1, W2, W3, wt);

    odefunc_mfma<<<B_TOTAL / M, BLOCK, 0, stream>>>(
        t, y, h, eps, b1, b2, b3, wt, out_f, out_dlogp);
}

// Round 3
// 407.441 us; speedup vs baseline: 5.0177x; 1.3494x over previous
//
#include <hip/hip_runtime.h>
#include <hip/hip_bf16.h>
#include <math.h>

#define B_TOTAL 262144
#define D 16
#define CTX 128
#define H 192
#define IN_DIM 145
#define KP1 160      // layer-1 K: [y(16), t(1), pad(15), h(128)]
#define M 32         // rows per block
#define BLOCK 256

typedef __attribute__((ext_vector_type(8))) short bf16x8;
typedef __attribute__((ext_vector_type(4))) float f32x4;

#define MFMA(a, b, c) __builtin_amdgcn_mfma_f32_16x16x32_bf16((a), (b), (c), 0, 0, 0)

__device__ __forceinline__ unsigned short f2bf_rne(float f) {
    unsigned u = __builtin_bit_cast(unsigned, f);
    u += 0x7FFFu + ((u >> 16) & 1u);
    return (unsigned short)(u >> 16);
}
// truncation-based hi/lo split: hi = trunc-bf16(v), lo = RNE(v - hi)
__device__ __forceinline__ void split2(float v, unsigned short& hi, unsigned short& lo) {
    unsigned u = __builtin_bit_cast(unsigned, v);
    hi = (unsigned short)(u >> 16);
    float hf = __builtin_bit_cast(float, u & 0xFFFF0000u);
    lo = f2bf_rne(v - hf);
}
// phi = 0.5(1+erf(x/sqrt2)) via A&S 7.1.26 (|eps|<=1.5e-7), exp shared with pdf
__device__ __forceinline__ void gelu_pair(float x, float& a, float& gp) {
    float s   = x * x;
    float e   = __expf(-0.5f * s);                       // e^{-x^2/2}
    float az  = fabsf(x) * 0.70710678118654752f;
    float t   = __builtin_amdgcn_rcpf(fmaf(0.3275911f, az, 1.0f));
    float p   = t * (0.254829592f + t * (-0.284496736f + t * (1.421413741f +
                t * (-1.453152027f + t * 1.061405429f))));
    float erfv = __builtin_copysignf(1.0f - p * e, x);
    float phi  = fmaf(0.5f, erfv, 0.5f);
    gp = fmaf(0.39894228040143268f * x, e, phi);          // phi + x*pdf
    a  = x * phi;
}

// ---------- pre-kernel: weights -> [N][K] bf16 in d_ws ----------
// Wt1: [192][160] @0 (k' map: 0-15->y rows, 16->t row(144), 17-31->0, 32+i->h row 16+i)
// Wt2: [192][192] @30720 ; Wt3: [16][192] @67584
__global__ void prep_weights(const float* __restrict__ W1,
                             const float* __restrict__ W2,
                             const float* __restrict__ W3,
                             unsigned short* __restrict__ wt)
{
    int i = blockIdx.x * 256 + threadIdx.x;
    if (i < H * KP1) {
        int n = i / KP1, kp = i % KP1;
        float v = 0.0f;
        if (kp < 16)       v = W1[kp * H + n];
        else if (kp == 16) v = W1[144 * H + n];
        else if (kp >= 32) v = W1[(kp - 16) * H + n];
        wt[i] = f2bf_rne(v);
        return;
    }
    i -= H * KP1;
    if (i < H * H) {
        int n = i / H, k = i % H;
        wt[30720 + i] = f2bf_rne(W2[k * H + n]);
        return;
    }
    i -= H * H;
    if (i < D * H) {
        int n = i / H, k = i % H;
        wt[67584 + i] = f2bf_rne(W3[k * D + n]);
    }
}

// ---------- main kernel ----------
__global__ __launch_bounds__(BLOCK, 3) void odefunc_mfma(
    const float* __restrict__ t_ptr,
    const float* __restrict__ y,
    const float* __restrict__ h,
    const float* __restrict__ eps,
    const float* __restrict__ b1,
    const float* __restrict__ b2,
    const float* __restrict__ b3,
    const unsigned short* __restrict__ wt,
    float* __restrict__ out_f,
    float* __restrict__ out_dlogp,
    float* __restrict__ out_dh)
{
    // LDS: Xh 10752 + Xl 2560 + Th 2560 + Tl 2560 + A 12800 + U 12800 = 44032 B -> 3 blk/CU
    __shared__ __align__(16) unsigned short Xh[M][168];   // full K=160 hi plane
    __shared__ __align__(16) unsigned short Xl[M][40];    // lo plane, chunk 0 only
    __shared__ __align__(16) unsigned short Th[M][40], Tl[M][40];
    __shared__ __align__(16) unsigned short A[M][200], U[M][200];

    const int tid  = threadIdx.x;
    const int lane = tid & 63;
    const int wv   = tid >> 6;
    const int quad = lane >> 4;
    const int l16  = lane & 15;
    const size_t r0 = (size_t)blockIdx.x * M;

    const unsigned short* Wt1 = wt;
    const unsigned short* Wt2 = wt + 30720;
    const unsigned short* Wt3 = wt + 67584;

    // ------- zero dh slice (overlaps with everything; no dependence) -------
    {
        float4 z4 = {0.f, 0.f, 0.f, 0.f};
        #pragma unroll
        for (int i = 0; i < 4; ++i) {
            int idx = tid + i * BLOCK;            // 1024 float4 = 32 rows x 32
            int r = idx >> 5, c4 = (idx & 31) * 4;
            *(float4*)(out_dh + (r0 + r) * CTX + c4) = z4;
        }
    }

    // ------------- stage inputs -------------
    {   // y (hi/lo) and eps (hi/lo): 2 x 128 float4 tasks
        int task = tid >> 7, idx = tid & 127;
        int r = idx >> 2, d4 = (idx & 3) * 4;
        const float* src = task ? eps : y;
        float4 v = *(const float4*)(src + (r0 + r) * D + d4);
        ushort4 hi, lo;
        split2(v.x, hi.x, lo.x); split2(v.y, hi.y, lo.y);
        split2(v.z, hi.z, lo.z); split2(v.w, hi.w, lo.w);
        if (task == 0) { *(ushort4*)&Xh[r][d4] = hi; *(ushort4*)&Xl[r][d4] = lo; }
        else           { *(ushort4*)&Th[r][d4] = hi; *(ushort4*)&Tl[r][d4] = lo; }
    }
    if (tid < M) {      // t column + pads (cols 16..31)
        int r = tid;
        float tv = t_ptr[0];
        unsigned short thi, tlo;
        split2(tv, thi, tlo);
        ushort4 z4 = {0, 0, 0, 0};
        ushort4 t4 = {thi, 0, 0, 0};
        ushort4 l4 = {tlo, 0, 0, 0};
        *(ushort4*)&Xh[r][16] = t4; *(ushort4*)&Xh[r][20] = z4;
        *(ushort4*)&Xh[r][24] = z4; *(ushort4*)&Xh[r][28] = z4;
        *(ushort4*)&Xl[r][16] = l4; *(ushort4*)&Xl[r][20] = z4;
        *(ushort4*)&Xl[r][24] = z4; *(ushort4*)&Xl[r][28] = z4;
        *(ushort4*)&Th[r][16] = z4; *(ushort4*)&Th[r][20] = z4;
        *(ushort4*)&Th[r][24] = z4; *(ushort4*)&Th[r][28] = z4;
        *(ushort4*)&Tl[r][16] = z4; *(ushort4*)&Tl[r][20] = z4;
        *(ushort4*)&Tl[r][24] = z4; *(ushort4*)&Tl[r][28] = z4;
    }
    #pragma unroll
    for (int i = 0; i < 4; ++i) {   // h: single bf16 plane, 1024 float4
        int idx = tid + i * BLOCK;
        int r = idx >> 5, c4 = (idx & 31) * 4;
        float4 v = *(const float4*)(h + (r0 + r) * CTX + c4);
        ushort4 hv = { f2bf_rne(v.x), f2bf_rne(v.y), f2bf_rne(v.z), f2bf_rne(v.w) };
        *(ushort4*)&Xh[r][32 + c4] = hv;
    }
    __syncthreads();

    const f32x4 zf = {0.f, 0.f, 0.f, 0.f};

    // ------------- layer 1 -------------
    f32x4 z[2][3], u[2][3];
    #pragma unroll
    for (int rt = 0; rt < 2; ++rt)
        #pragma unroll
        for (int j = 0; j < 3; ++j) { z[rt][j] = zf; u[rt][j] = zf; }

    bf16x8 w1f[3][5];
    #pragma unroll
    for (int j = 0; j < 3; ++j) {
        int n = (wv * 3 + j) * 16 + l16;
        #pragma unroll
        for (int kc = 0; kc < 5; ++kc)
            w1f[j][kc] = *(const bf16x8*)(Wt1 + n * KP1 + kc * 32 + quad * 8);
    }
    #pragma unroll
    for (int kc = 0; kc < 5; ++kc)
        #pragma unroll
        for (int rt = 0; rt < 2; ++rt) {
            bf16x8 ah = *(const bf16x8*)&Xh[rt * 16 + l16][kc * 32 + quad * 8];
            #pragma unroll
            for (int j = 0; j < 3; ++j) z[rt][j] = MFMA(ah, w1f[j][kc], z[rt][j]);
        }
    #pragma unroll
    for (int rt = 0; rt < 2; ++rt) {   // chunk-0 lo + tangent hi/lo
        int m = rt * 16 + l16;
        bf16x8 al = *(const bf16x8*)&Xl[m][quad * 8];
        bf16x8 th = *(const bf16x8*)&Th[m][quad * 8];
        bf16x8 tl = *(const bf16x8*)&Tl[m][quad * 8];
        #pragma unroll
        for (int j = 0; j < 3; ++j) {
            z[rt][j] = MFMA(al, w1f[j][0], z[rt][j]);
            u[rt][j] = MFMA(th, w1f[j][0], u[rt][j]);
            u[rt][j] = MFMA(tl, w1f[j][0], u[rt][j]);
        }
    }
    // epilogue 1 (disjoint LDS from X/T: no barrier needed before writes)
    #pragma unroll
    for (int j = 0; j < 3; ++j) {
        int n = (wv * 3 + j) * 16 + l16;
        float bb = b1[n];
        #pragma unroll
        for (int rt = 0; rt < 2; ++rt)
            #pragma unroll
            for (int rg = 0; rg < 4; ++rg) {
                int m = rt * 16 + quad * 4 + rg;
                float x = z[rt][j][rg] + bb;
                float a, gp; gelu_pair(x, a, gp);
                A[m][n] = f2bf_rne(a);
                U[m][n] = f2bf_rne(u[rt][j][rg] * gp);
            }
    }
    __syncthreads();

    // ------------- layer 2 -------------
    f32x4 z2[2][3], u2[2][3];
    #pragma unroll
    for (int rt = 0; rt < 2; ++rt)
        #pragma unroll
        for (int j = 0; j < 3; ++j) { z2[rt][j] = zf; u2[rt][j] = zf; }

    bf16x8 w2f[3][6];
    #pragma unroll
    for (int j = 0; j < 3; ++j) {
        int n = (wv * 3 + j) * 16 + l16;
        #pragma unroll
        for (int kc = 0; kc < 6; ++kc)
            w2f[j][kc] = *(const bf16x8*)(Wt2 + n * H + kc * 32 + quad * 8);
    }
    #pragma unroll
    for (int kc = 0; kc < 6; ++kc)
        #pragma unroll
        for (int rt = 0; rt < 2; ++rt) {
            int m = rt * 16 + l16, o = kc * 32 + quad * 8;
            bf16x8 av = *(const bf16x8*)&A[m][o];
            bf16x8 uv = *(const bf16x8*)&U[m][o];
            #pragma unroll
            for (int j = 0; j < 3; ++j) {
                z2[rt][j] = MFMA(av, w2f[j][kc], z2[rt][j]);
                u2[rt][j] = MFMA(uv, w2f[j][kc], u2[rt][j]);
            }
        }
    __syncthreads();   // all A/U reads done before overwrite
    #pragma unroll
    for (int j = 0; j < 3; ++j) {
        int n = (wv * 3 + j) * 16 + l16;
        float bb = b2[n];
        #pragma unroll
        for (int rt = 0; rt < 2; ++rt)
            #pragma unroll
            for (int rg = 0; rg < 4; ++rg) {
                int m = rt * 16 + quad * 4 + rg;
                float x = z2[rt][j][rg] + bb;
                float a, gp; gelu_pair(x, a, gp);
                A[m][n] = f2bf_rne(a);
                U[m][n] = f2bf_rne(u2[rt][j][rg] * gp);
            }
    }
    __syncthreads();

    // ------------- layer 3 + outputs -------------
    // wave 0: rows 0-15 value | wave 1: rows 0-15 tangent | waves 2/3: rows 16-31
    {
        const int strm = wv & 1, rt = wv >> 1;
        const unsigned short (*P)[200] = strm ? U : A;

        bf16x8 w3f[6];
        #pragma unroll
        for (int kc = 0; kc < 6; ++kc)
            w3f[kc] = *(const bf16x8*)(Wt3 + l16 * H + kc * 32 + quad * 8);

        f32x4 acc = zf;
        #pragma unroll
        for (int kc = 0; kc < 6; ++kc) {
            bf16x8 xv = *(const bf16x8*)&P[rt * 16 + l16][kc * 32 + quad * 8];
            acc = MFMA(xv, w3f[kc], acc);
        }

        if (strm == 0) {
            float bb = b3[l16];
            #pragma unroll
            for (int rg = 0; rg < 4; ++rg) {
                int m = rt * 16 + quad * 4 + rg;
                out_f[(r0 + m) * D + l16] = acc[rg] + bb;
            }
        } else {
            float pr[4];
            #pragma unroll
            for (int rg = 0; rg < 4; ++rg) {
                int m = rt * 16 + quad * 4 + rg;
                pr[rg] = acc[rg] * eps[(r0 + m) * D + l16];
            }
            #pragma unroll
            for (int sh = 1; sh < 16; sh <<= 1)
                #pragma unroll
                for (int rg = 0; rg < 4; ++rg)
                    pr[rg] += __shfl_xor(pr[rg], sh, 64);
            if (l16 == 0)
                #pragma unroll
                for (int rg = 0; rg < 4; ++rg)
                    out_dlogp[r0 + rt * 16 + quad * 4 + rg] = -pr[rg];
        }
    }
}

extern "C" void kernel_launch(void* const* d_in, const int* in_sizes, int n_in,
                              void* d_out, int out_size, void* d_ws, size_t ws_size,
                              hipStream_t stream)
{
    const float* t   = (const float*)d_in[0];
    const float* y   = (const float*)d_in[1];
    const float* h   = (const float*)d_in[3];
    const float* eps = (const float*)d_in[4];
    const float* W1  = (const float*)d_in[5];
    const float* b1  = (const float*)d_in[6];
    const float* W2  = (const float*)d_in[7];
    const float* b2  = (const float*)d_in[8];
    const float* W3  = (const float*)d_in[9];
    const float* b3  = (const float*)d_in[10];

    float* out       = (float*)d_out;
    float* out_f     = out;
    float* out_dlogp = out + (size_t)B_TOTAL * D;
    float* out_dh    = out + (size_t)B_TOTAL * (D + 1);

    unsigned short* wt = (unsigned short*)d_ws;

    int prep_elems = H * KP1 + H * H + D * H;   // 70656
    prep_weights<<<(prep_elems + 255) / 256, 256, 0, stream>>>(W1, W2, W3, wt);

    odefunc_mfma<<<B_TOTAL / M, BLOCK, 0, stream>>>(
        t, y, h, eps, b1, b2, b3, wt, out_f, out_dlogp, out_dh);
}